// Round 19
// baseline (163.308 us; speedup 1.0000x reference)
//
#include <hip/hip_runtime.h>

#define N_ROWS 32768
#define DIM 256
#define KCODES 1024

#define Q_N (N_ROWS * DIM)          // 8388608
#define IDX_OFF Q_N                 // 8388608
#define ZERO_OFF (Q_N + N_ROWS)     // 8421376
#define LOSS_OFF (ZERO_OFF + 1)
#define PERP_OFF (ZERO_OFF + 2)

// Scaled-acc units: acc' = 512 + 512*sen - 1024*dot (=1024*(score/2)+512).
// Required window T = np-flip window (0.031) + 2*fast-path error (~0.027)
// + 2*key-trunc (2*0.0039) ~= 0.093. AMBIG_S = 0.12 covers with slack.
#define AMBIG_S  0.12f

#define TC 64                 // codes per fragment tile
#define HALF_TILES 8          // tiles per codebook half (512 codes)
#define PAIR_GRID 768
#define FULL_GRID 1024
#define GATHER_BLOCKS 1024
#define GATHER_ITERS 8        // 1024*256*8 = 2M float4 = N_ROWS*DIM/4

typedef __attribute__((ext_vector_type(8))) _Float16 f16x8;
typedef __attribute__((ext_vector_type(4))) float f32x4;
typedef unsigned short u16;
typedef unsigned long long u64;

// ws layout (bytes):
//   [0, 4096)            sen float[K]
//   [4096, 8192)         hist uint[K]
//   [8192, 8196)         uint pair_count
//   [8196, 8200)         uint full_count
//   [8448, 270592)       pairlist uint2[32768]  {row, c1<<16|c2}
//   [270592, 401664)     fulllist uint[32768]
//   [401664, 925952)     eswz u16[262144]  fp16(-1024*e) in FRAGMENT order:
//                        16B chunk g = half*16384 + tt*2048 + dc*256 + ct*64
//                        + lane; lane l = code (ct*16 + (l&15)), dims
//                        dc*32+(l>>4)*8..+8 -> wave loads are lane-contiguous
//   [925952, 934144)     partials double[1024]  (per-block loss sums)
//   [934144, 1196288)    fullkey u64[32768]  (per-fulllist-slot packed min)
//   [1196288, 2769152)   cand u32[2][32768][6]  (per-half top-3: {a,code}x3)

__device__ inline u16 f16bits(_Float16 h) {
    union { _Float16 h; u16 u; } x; x.h = h; return x.u;
}

__device__ inline bool lexless(float av, int ai, float bv, int bi) {
    return av < bv || (av == bv && ai < bi);
}

// fused: init(hist/counters) + accurate ||e||^2 + fragment-order eswz.
// Part A (all 256 threads): sen for 4 codes/block.
// Part B (t<128): one 16B eswz chunk per thread (256 blocks x 128 = 32768).
__global__ __launch_bounds__(256) void vq_prep_cb(const float* __restrict__ cb,
                                                  float* __restrict__ sen,
                                                  u16* __restrict__ eswz,
                                                  unsigned* __restrict__ hist,
                                                  unsigned* __restrict__ pcnt,
                                                  unsigned* __restrict__ fcnt) {
    int b = blockIdx.x, t = threadIdx.x;
    if (b < 4) {
        hist[b * 256 + t] = 0u;
        if (b == 0 && t == 0) { *pcnt = 0u; *fcnt = 0u; }
    }
    {   // part A: sen
        int code = b * 4 + (t >> 6);
        int lane = t & 63;
        float4 v = *(const float4*)(cb + (size_t)code * DIM + lane * 4);
        double s = (double)v.x * v.x + (double)v.y * v.y + (double)v.z * v.z + (double)v.w * v.w;
        #pragma unroll
        for (int off = 32; off; off >>= 1) s += __shfl_down(s, off, 64);
        if (lane == 0) sen[code] = (float)s;
    }
    if (t < 128) {   // part B: one fragment chunk
        int g = b * 128 + t;
        int lane = g & 63;
        int ct = (g >> 6) & 3;
        int dc = (g >> 8) & 7;
        int tt = (g >> 11) & 7;
        int half = g >> 14;
        int code = half * 512 + tt * TC + ct * 16 + (lane & 15);
        int d0 = dc * 32 + (lane >> 4) * 8;
        const float* src = cb + (size_t)code * DIM + d0;
        float4 f0 = *(const float4*)src;
        float4 f1 = *(const float4*)(src + 4);
        ushort4 lo, hi;
        lo.x = f16bits((_Float16)(-1024.0f * f0.x));
        lo.y = f16bits((_Float16)(-1024.0f * f0.y));
        lo.z = f16bits((_Float16)(-1024.0f * f0.z));
        lo.w = f16bits((_Float16)(-1024.0f * f0.w));
        hi.x = f16bits((_Float16)(-1024.0f * f1.x));
        hi.y = f16bits((_Float16)(-1024.0f * f1.y));
        hi.z = f16bits((_Float16)(-1024.0f * f1.z));
        hi.w = f16bits((_Float16)(-1024.0f * f1.w));
        *(ushort4*)(eswz + (size_t)g * 8) = lo;
        *(ushort4*)(eswz + (size_t)g * 8 + 4) = hi;
    }
}

// fp16 MFMA distance-argmin, NO LDS / NO BARRIERS: B-fragments streamed
// directly from the L2-resident fragment-ordered eswz (coalesced dwordx4,
// lane-contiguous). 512 blocks = 256 row-blocks x 2 halves; 4 waves x 32
// rows/wave (2 A-groups). Waves free-run; latency hidden by TLP (8 waves/CU)
// + ILP (unroll-2 tile loop = 64 loads in flight). Bytes & MFMA operands
// bit-identical to the LDS versions (rounds 12-18).
__global__ __launch_bounds__(256, 2) void vq_mfma(const float* __restrict__ z,
                                                  const u16* __restrict__ eswz,
                                                  const float* __restrict__ sen,
                                                  unsigned* __restrict__ cand) {
    const int tid = threadIdx.x;
    const int wid = tid >> 6;        // 0..3
    const int lane = tid & 63;
    const int col16 = lane & 15;
    const int koct = lane >> 4;
    const int rowblk = blockIdx.x & 255;
    const int half = blockIdx.x >> 8;
    const int rowbase = rowblk * 128 + wid * 32;

    // A fragments: 2 row-groups x 8 d-chunks, fp32->fp16 RNE
    f16x8 zf[2][8];
    #pragma unroll
    for (int g = 0; g < 2; ++g) {
        const float* zp = z + (size_t)(rowbase + g * 16 + col16) * DIM + koct * 8;
        #pragma unroll
        for (int dc = 0; dc < 8; ++dc) {
            float4 f0 = *(const float4*)(zp + dc * 32);
            float4 f1 = *(const float4*)(zp + dc * 32 + 4);
            f16x8 h;
            h[0] = (_Float16)f0.x; h[1] = (_Float16)f0.y;
            h[2] = (_Float16)f0.z; h[3] = (_Float16)f0.w;
            h[4] = (_Float16)f1.x; h[5] = (_Float16)f1.y;
            h[6] = (_Float16)f1.z; h[7] = (_Float16)f1.w;
            zf[g][dc] = h;
        }
    }

    unsigned k1[2][4], k2[2][4], k3[2][4];
    #pragma unroll
    for (int g = 0; g < 2; ++g)
        #pragma unroll
        for (int r = 0; r < 4; ++r) { k1[g][r] = k2[g][r] = k3[g][r] = 0xFFFFFFFFu; }

    // fragment base for this half; per-(tt,dc,ct) chunk at lane*16
    const u16* fb = eswz + (size_t)half * 16384 * 8 + (size_t)lane * 8;

    #pragma unroll 2
    for (int tt = 0; tt < HALF_TILES; ++tt) {
        f32x4 acc[2][4];
        #pragma unroll
        for (int ct = 0; ct < 4; ++ct) {
            float sv = sen[half * 512 + tt * TC + ct * 16 + col16];
            float b0 = fmaf(512.0f, sv, 512.0f);   // positive-bias C init
            acc[0][ct] = (f32x4){b0, b0, b0, b0};
            acc[1][ct] = (f32x4){b0, b0, b0, b0};
        }
        #pragma unroll
        for (int dc = 0; dc < 8; ++dc) {
            #pragma unroll
            for (int ct = 0; ct < 4; ++ct) {
                // chunk index: tt*2048 + dc*256 + ct*64 (+lane) u16-elems *8/lane
                f16x8 bv = *(const f16x8*)(fb + ((size_t)tt * 2048 + dc * 256 + ct * 64) * 8);
                acc[0][ct] = __builtin_amdgcn_mfma_f32_16x16x32_f16(zf[0][dc], bv, acc[0][ct], 0, 0, 0);
                acc[1][ct] = __builtin_amdgcn_mfma_f32_16x16x32_f16(zf[1][dc], bv, acc[1][ct], 0, 0, 0);
            }
        }
        #pragma unroll
        for (int ct = 0; ct < 4; ++ct) {
            const unsigned lidx = (unsigned)(tt * 4 + ct);
            #pragma unroll
            for (int g = 0; g < 2; ++g)
                #pragma unroll
                for (int r = 0; r < 4; ++r) {
                    float s = acc[g][ct][r];
                    unsigned key = (__float_as_uint(s) & 0xFFFFFFC0u) | lidx;
                    unsigned o1 = k1[g][r];
                    k1[g][r] = min(o1, key);                      // new min
                    k3[g][r] = min(k3[g][r], max(k2[g][r], key)); // new 3rd
                    k2[g][r] = min(max(key, o1), k2[g][r]);       // med
                }
        }
    }

    #pragma unroll
    for (int g = 0; g < 2; ++g)
        #pragma unroll
        for (int r = 0; r < 4; ++r) {
            float a1 = __uint_as_float(k1[g][r] & 0xFFFFFFC0u);
            float a2 = __uint_as_float(k2[g][r] & 0xFFFFFFC0u);
            float a3 = __uint_as_float(k3[g][r] & 0xFFFFFFC0u);
            int l1 = (int)(k1[g][r] & 63u), l2 = (int)(k2[g][r] & 63u), l3 = (int)(k3[g][r] & 63u);
            int b1 = half * 512 + (l1 >> 2) * TC + (l1 & 3) * 16 + col16;
            int b2 = half * 512 + (l2 >> 2) * TC + (l2 & 3) * 16 + col16;
            int b3 = half * 512 + (l3 >> 2) * TC + (l3 & 3) * 16 + col16;
            #pragma unroll
            for (int m = 1; m < 16; m <<= 1) {
                float o1 = __shfl_xor(a1, m, 64), o2 = __shfl_xor(a2, m, 64), o3 = __shfl_xor(a3, m, 64);
                int p1 = __shfl_xor(b1, m, 64), p2 = __shfl_xor(b2, m, 64), p3 = __shfl_xor(b3, m, 64);
                #pragma unroll
                for (int k = 0; k < 3; ++k) {
                    float ov = (k == 0) ? o1 : (k == 1) ? o2 : o3;
                    int oi = (k == 0) ? p1 : (k == 1) ? p2 : p3;
                    if (lexless(ov, oi, a1, b1)) {
                        a3 = a2; b3 = b2; a2 = a1; b2 = b1; a1 = ov; b1 = oi;
                    } else if (lexless(ov, oi, a2, b2)) {
                        a3 = a2; b3 = b2; a2 = ov; b2 = oi;
                    } else if (lexless(ov, oi, a3, b3)) {
                        a3 = ov; b3 = oi;
                    }
                }
            }
            if (col16 == 0) {
                int row = rowbase + g * 16 + koct * 4 + r;
                unsigned* cp = cand + ((size_t)half * N_ROWS + row) * 6;
                cp[0] = __float_as_uint(a1); cp[1] = (unsigned)b1;
                cp[2] = __float_as_uint(a2); cp[3] = (unsigned)b2;
                cp[4] = __float_as_uint(a3); cp[5] = (unsigned)b3;
            }
        }
}

// merge the two halves' top-3 -> global top-3 (identical lexless insertion),
// write idx, classify pair/full with the same thresholds as rounds 12-18.
__global__ __launch_bounds__(256) void vq_merge(const unsigned* __restrict__ cand,
                                                float* __restrict__ idx_out,
                                                unsigned* __restrict__ pcnt,
                                                uint2* __restrict__ pairlist,
                                                unsigned* __restrict__ fcnt,
                                                unsigned* __restrict__ fulllist,
                                                u64* __restrict__ fullkey) {
    int row = blockIdx.x * 256 + threadIdx.x;
    const unsigned* cA = cand + (size_t)row * 6;
    const unsigned* cB = cand + ((size_t)N_ROWS + row) * 6;
    float a1 = __uint_as_float(cA[0]), a2 = __uint_as_float(cA[2]), a3 = __uint_as_float(cA[4]);
    int   b1 = (int)cA[1], b2 = (int)cA[3], b3 = (int)cA[5];
    float o1 = __uint_as_float(cB[0]), o2 = __uint_as_float(cB[2]), o3 = __uint_as_float(cB[4]);
    int   p1 = (int)cB[1], p2 = (int)cB[3], p3 = (int)cB[5];
    #pragma unroll
    for (int k = 0; k < 3; ++k) {
        float ov = (k == 0) ? o1 : (k == 1) ? o2 : o3;
        int oi = (k == 0) ? p1 : (k == 1) ? p2 : p3;
        if (lexless(ov, oi, a1, b1)) {
            a3 = a2; b3 = b2; a2 = a1; b2 = b1; a1 = ov; b1 = oi;
        } else if (lexless(ov, oi, a2, b2)) {
            a3 = a2; b3 = b2; a2 = ov; b2 = oi;
        } else if (lexless(ov, oi, a3, b3)) {
            a3 = ov; b3 = oi;
        }
    }
    idx_out[row] = (float)b1;
    if (a2 - a1 < AMBIG_S) {
        if (a3 - a1 < AMBIG_S) {               // >=2 contenders near a1
            unsigned slot = atomicAdd(fcnt, 1u);
            fulllist[slot] = (unsigned)row;
            fullkey[slot] = ~0ull;
        } else {                               // exactly one contender
            unsigned slot = atomicAdd(pcnt, 1u);
            pairlist[slot] = make_uint2((unsigned)row,
                                        ((unsigned)b1 << 16) | (unsigned)b2);
        }
    }
}

// np-pairwise ||z||^2, replicated in every 16-lane group.
__device__ inline float szn_wave(const float* __restrict__ zrow, int lane) {
    int sub = lane & 15;
    int hb = sub >> 3;
    int j = sub & 7;
    const float* a = zrow + hb * 128 + j;
    float v0 = a[0];
    float c = __fmul_rn(v0, v0);
    #pragma unroll
    for (int i = 1; i < 16; ++i) {
        float w = a[8 * i];
        c = __fadd_rn(c, __fmul_rn(w, w));
    }
    float p;
    p = __shfl_xor(c, 1, 64); c = __fadd_rn(c, p);
    p = __shfl_xor(c, 2, 64); c = __fadd_rn(c, p);
    p = __shfl_xor(c, 4, 64); c = __fadd_rn(c, p);
    p = __shfl_xor(c, 8, 64); c = __fadd_rn(c, p);
    return c;
}

// pair rescore: wave-per-row, 2 exact fp64 dots, np-emulated dref, lex-min.
__global__ __launch_bounds__(256) void vq_fixpair(const float* __restrict__ z,
                                                  const float* __restrict__ cb,
                                                  const float* __restrict__ sen,
                                                  const unsigned* __restrict__ pcnt,
                                                  const uint2* __restrict__ pairlist,
                                                  float* __restrict__ idx_out) {
    int wave = blockIdx.x * 4 + (threadIdx.x >> 6);
    int lane = threadIdx.x & 63;
    int half = lane >> 5, s5 = lane & 31;
    int n = (int)*pcnt;
    for (int w = wave; w < n; w += PAIR_GRID * 4) {
        uint2 pr = pairlist[w];
        int row = (int)pr.x;
        int c1 = (int)(pr.y >> 16), c2 = (int)(pr.y & 0xffffu);
        const float* zrow = z + (size_t)row * DIM;
        float sz = szn_wave(zrow, lane);
        int c = half ? c2 : c1;
        const float* zp = zrow + s5 * 8;
        const float* ep = cb + (size_t)c * DIM + s5 * 8;
        float4 za = *(const float4*)zp, zb = *(const float4*)(zp + 4);
        float4 ea = *(const float4*)ep, eb = *(const float4*)(ep + 4);
        double acc = (double)ea.x * za.x + (double)ea.y * za.y
                   + (double)ea.z * za.z + (double)ea.w * za.w
                   + (double)eb.x * zb.x + (double)eb.y * zb.y
                   + (double)eb.z * zb.z + (double)eb.w * zb.w;
        #pragma unroll
        for (int m = 1; m < 32; m <<= 1) acc += __shfl_xor(acc, m, 64);
        double d2 = __shfl(acc, 32, 64);            // lane0 reads half-1 dot
        if (lane == 0) {
            float A1 = __fadd_rn(sz, sen[c1]);
            float dref1 = __fmaf_rn(-2.0f, (float)acc, A1);
            float A2 = __fadd_rn(sz, sen[c2]);
            float dref2 = __fmaf_rn(-2.0f, (float)d2, A2);
            int win = lexless(dref1, c1, dref2, c2) ? c1 : c2;
            idx_out[row] = (float)win;
        }
    }
}

// full np-exact rescan, chunked: work item = (full row, 64-code chunk), one
// wave each; LDS [64][257]; lane=code 4-chain fp64 dot; 6-step butterfly;
// atomicMin(u64 packed (dref_bits<<32)|code) = global np first-index argmin.
__global__ __launch_bounds__(64) void vq_fixfull(const float* __restrict__ z,
                                                 const float* __restrict__ cb,
                                                 const float* __restrict__ sen,
                                                 const unsigned* __restrict__ fcnt,
                                                 const unsigned* __restrict__ fulllist,
                                                 u64* __restrict__ fullkey) {
    __shared__ float et[64 * 257];
    __shared__ float zs[DIM];
    const int t = threadIdx.x;
    unsigned nitems = (*fcnt) * 16u;
    for (unsigned item = blockIdx.x; item < nitems; item += FULL_GRID) {
        int slot = (int)(item >> 4);
        int row = (int)fulllist[slot];
        int c0 = (int)(item & 15u) * 64;
        #pragma unroll 8
        for (int i = 0; i < 64; ++i) {
            int g4 = i * 64 + t;
            int code = g4 >> 6, d0 = (g4 & 63) * 4;
            float4 v = *(const float4*)(cb + (size_t)(c0 + code) * DIM + d0);
            int base = code * 257 + d0;
            et[base] = v.x; et[base + 1] = v.y; et[base + 2] = v.z; et[base + 3] = v.w;
        }
        {
            float4 v = *(const float4*)(z + (size_t)row * DIM + t * 4);
            zs[t * 4] = v.x; zs[t * 4 + 1] = v.y; zs[t * 4 + 2] = v.z; zs[t * 4 + 3] = v.w;
        }
        __syncthreads();
        float sz = szn_wave(zs, t);
        const int rb = t * 257;
        double a0 = 0.0, a1 = 0.0, a2 = 0.0, a3 = 0.0;
        #pragma unroll 16
        for (int d = 0; d < DIM; d += 4) {
            a0 += (double)et[rb + d]     * (double)zs[d];
            a1 += (double)et[rb + d + 1] * (double)zs[d + 1];
            a2 += (double)et[rb + d + 2] * (double)zs[d + 2];
            a3 += (double)et[rb + d + 3] * (double)zs[d + 3];
        }
        double dot = (a0 + a1) + (a2 + a3);
        int c = c0 + t;
        float A = __fadd_rn(sz, sen[c]);
        float dref = __fmaf_rn(-2.0f, (float)dot, A);
        float bv = dref; int bi = c;
        #pragma unroll
        for (int m = 1; m < 64; m <<= 1) {
            float ov = __shfl_xor(bv, m, 64);
            int oi = __shfl_xor(bi, m, 64);
            if (lexless(ov, oi, bv, bi)) { bv = ov; bi = oi; }
        }
        if (t == 0) {
            u64 key = ((u64)__float_as_uint(bv) << 32) | (unsigned)bi;
            atomicMin(&fullkey[slot], key);
        }
        __syncthreads();
    }
}

// unpack per-slot winners -> idx (runs after fixfull, before gather)
__global__ __launch_bounds__(256) void vq_resolve(const unsigned* __restrict__ fcnt,
                                                  const unsigned* __restrict__ fulllist,
                                                  const u64* __restrict__ fullkey,
                                                  float* __restrict__ idx_out) {
    int n = (int)*fcnt;
    for (int i = threadIdx.x; i < n; i += 256)
        idx_out[fulllist[i]] = (float)(unsigned)(fullkey[i] & 0xFFFFFFFFu);
}

// quantized_ste + commitment loss + histogram. Per-block loss partials.
__global__ __launch_bounds__(256) void vq_gather(const float* __restrict__ z,
                                                 const float* __restrict__ cb,
                                                 const float* __restrict__ idxf,
                                                 float* __restrict__ qout,
                                                 unsigned* __restrict__ hist,
                                                 double* __restrict__ partials) {
    const int tid = threadIdx.x;
    double lacc = 0.0;
    #pragma unroll
    for (int it = 0; it < GATHER_ITERS; ++it) {
        int g = it * (GATHER_BLOCKS * 256) + blockIdx.x * 256 + tid;
        int row = g >> 6, c4 = g & 63;
        int idx = (int)idxf[row];
        if (c4 == 0) atomicAdd(&hist[idx], 1u);
        float4 zv = *(const float4*)(z + (size_t)g * 4);
        float4 qv = *(const float4*)(cb + (size_t)idx * DIM + c4 * 4);
        float dx = qv.x - zv.x, dy = qv.y - zv.y, dz = qv.z - zv.z, dw = qv.w - zv.w;
        float4 o;
        o.x = zv.x + dx; o.y = zv.y + dy; o.z = zv.z + dz; o.w = zv.w + dw;
        *(float4*)(qout + (size_t)g * 4) = o;
        lacc += (double)(dx * dx + dy * dy + dz * dz + dw * dw);
    }
    #pragma unroll
    for (int off = 32; off; off >>= 1) lacc += __shfl_down(lacc, off, 64);
    __shared__ double wsum[4];
    int lane = tid & 63, wv = tid >> 6;
    if (lane == 0) wsum[wv] = lacc;
    __syncthreads();
    if (tid == 0)
        partials[blockIdx.x] = (wsum[0] + wsum[1]) + (wsum[2] + wsum[3]);
}

// reduce 1024 loss partials (double) + hist entropy -> 3 scalars
__global__ __launch_bounds__(1024) void vq_finalize(const unsigned* __restrict__ hist,
                                                    const double* __restrict__ partials,
                                                    float* __restrict__ out) {
    __shared__ float red[1024];
    __shared__ double redd[1024];
    int t = threadIdx.x;
    float p = (float)hist[t] * (1.0f / (float)N_ROWS);
    red[t] = p * logf(p + 1e-10f);
    redd[t] = partials[t];
    __syncthreads();
    for (int s = 512; s; s >>= 1) {
        if (t < s) { red[t] += red[t + s]; redd[t] += redd[t + s]; }
        __syncthreads();
    }
    if (t == 0) {
        out[ZERO_OFF] = 0.0f;
        out[LOSS_OFF] = (float)(0.25 * redd[0] / (double)Q_N);
        out[PERP_OFF] = expf(-red[0]);
    }
}

extern "C" void kernel_launch(void* const* d_in, const int* in_sizes, int n_in,
                              void* d_out, int out_size, void* d_ws, size_t ws_size,
                              hipStream_t stream) {
    const float* z = (const float*)d_in[0];
    const float* cb = (const float*)d_in[1];
    float* out = (float*)d_out;

    float* sen = (float*)d_ws;
    unsigned* hist = (unsigned*)((char*)d_ws + 4096);
    unsigned* pcnt = (unsigned*)((char*)d_ws + 8192);
    unsigned* fcnt = (unsigned*)((char*)d_ws + 8196);
    uint2* pairlist = (uint2*)((char*)d_ws + 8448);
    unsigned* fulllist = (unsigned*)((char*)d_ws + 270592);
    u16* eswz = (u16*)((char*)d_ws + 401664);
    double* partials = (double*)((char*)d_ws + 925952);
    u64* fullkey = (u64*)((char*)d_ws + 934144);
    unsigned* cand = (unsigned*)((char*)d_ws + 1196288);

    vq_prep_cb<<<KCODES / 4, 256, 0, stream>>>(cb, sen, eswz, hist, pcnt, fcnt);
    vq_mfma<<<512, 256, 0, stream>>>(z, eswz, sen, cand);
    vq_merge<<<N_ROWS / 256, 256, 0, stream>>>(cand, out + IDX_OFF,
                                               pcnt, pairlist, fcnt, fulllist, fullkey);
    vq_fixpair<<<PAIR_GRID, 256, 0, stream>>>(z, cb, sen, pcnt, pairlist, out + IDX_OFF);
    vq_fixfull<<<FULL_GRID, 64, 0, stream>>>(z, cb, sen, fcnt, fulllist, fullkey);
    vq_resolve<<<1, 256, 0, stream>>>(fcnt, fulllist, fullkey, out + IDX_OFF);
    vq_gather<<<GATHER_BLOCKS, 256, 0, stream>>>(z, cb, out + IDX_OFF, out, hist, partials);
    vq_finalize<<<1, 1024, 0, stream>>>(hist, partials, out);
}

// Round 20
// 126.248 us; speedup vs baseline: 1.2935x; 1.2935x over previous
//
#include <hip/hip_runtime.h>

#define N_ROWS 32768
#define DIM 256
#define KCODES 1024

#define Q_N (N_ROWS * DIM)          // 8388608
#define IDX_OFF Q_N                 // 8388608
#define ZERO_OFF (Q_N + N_ROWS)     // 8421376
#define LOSS_OFF (ZERO_OFF + 1)
#define PERP_OFF (ZERO_OFF + 2)

// Scaled-acc units: acc' = 512 + 512*sen - 1024*dot (=1024*(score/2)+512).
// Required window T = np-flip window (0.031) + 2*fast-path error (~0.027)
// + 2*key-trunc (2*0.0039) ~= 0.093. AMBIG_S = 0.12 covers with slack.
#define AMBIG_S  0.12f

#define TC 64                 // codes per LDS tile (mfma)
#define HALF_TILES 8          // tiles per codebook half (512 codes)
#define PAIR_GRID 768
#define FIX_GRID 1024         // [0,768) pair, [768,1024) full
#define GATHER_BLOCKS 1024
#define GATHER_ITERS 8        // 1024*256*8 = 2M float4 = N_ROWS*DIM/4

typedef __attribute__((ext_vector_type(8))) _Float16 f16x8;
typedef __attribute__((ext_vector_type(4))) float f32x4;
typedef unsigned short u16;
typedef unsigned long long u64;

// ws layout (bytes):
//   [0, 4096)            sen float[K]
//   [4096, 8192)         hist uint[K]
//   [8192, 8196)         uint pair_count
//   [8196, 8200)         uint full_count
//   [8200, 8204)         uint gather_done
//   [8448, 270592)       pairlist uint2[32768]  {row, c1<<16|c2}
//   [270592, 401664)     fulllist uint[32768]
//   [401664, 925952)     e16 u16[262144]  (fp16 of -1024*e, row-major)
//   [925952, 934144)     partials double[1024]  (per-block loss sums)
//   [934144, 1196288)    fullkey u64[32768]  (per-fulllist-slot packed min)
//   [1196288, 1327360)   fulldone uint[32768]
// cand u32[2][32768][6] lives in d_out's q region (scratch until vq_gather).

__device__ inline u16 f16bits(_Float16 h) {
    union { _Float16 h; u16 u; } x; x.h = h; return x.u;
}

__device__ inline bool lexless(float av, int ai, float bv, int bi) {
    return av < bv || (av == bv && ai < bi);
}

typedef __attribute__((address_space(3))) unsigned int as3_uint;
typedef __attribute__((address_space(1))) const unsigned int as1_uint;
__device__ inline void gload_lds16(const void* g, void* l) {
    __builtin_amdgcn_global_load_lds((as1_uint*)g, (as3_uint*)l, 16, 0, 0);
}

// fused: init(hist/counters/fulldone) + accurate ||e||^2 + e16 = fp16(-1024*e).
__global__ __launch_bounds__(256) void vq_prep_cb(const float* __restrict__ cb,
                                                  float* __restrict__ sen,
                                                  u16* __restrict__ e16,
                                                  unsigned* __restrict__ hist,
                                                  unsigned* __restrict__ pcnt,
                                                  unsigned* __restrict__ fcnt,
                                                  unsigned* __restrict__ gdone,
                                                  unsigned* __restrict__ fulldone) {
    int b = blockIdx.x, t = threadIdx.x;
    if (b < 4) {
        hist[b * 256 + t] = 0u;
        if (b == 0 && t == 0) { *pcnt = 0u; *fcnt = 0u; *gdone = 0u; }
    }
    if (b < 128) fulldone[b * 256 + t] = 0u;
    int code = b * 4 + (t >> 6);
    int lane = t & 63;
    size_t eoff = (size_t)code * DIM + lane * 4;
    float4 v = *(const float4*)(cb + eoff);
    double s = (double)v.x * v.x + (double)v.y * v.y + (double)v.z * v.z + (double)v.w * v.w;
    #pragma unroll
    for (int off = 32; off; off >>= 1) s += __shfl_down(s, off, 64);
    if (lane == 0) sen[code] = (float)s;
    ushort4 us;
    us.x = f16bits((_Float16)(-1024.0f * v.x));
    us.y = f16bits((_Float16)(-1024.0f * v.y));
    us.z = f16bits((_Float16)(-1024.0f * v.z));
    us.w = f16bits((_Float16)(-1024.0f * v.w));
    *(ushort4*)(e16 + eoff) = us;
}

// fp16 MFMA distance-argmin, SPLIT-K halves + counted-vmcnt barriers
// (round-18 version verbatim: best measured structure, ~48us).
__global__ __launch_bounds__(256, 2) void vq_mfma(const float* __restrict__ z,
                                                  const u16* __restrict__ e16,
                                                  const float* __restrict__ sen,
                                                  unsigned* __restrict__ cand) {
    __shared__ char lds[2][32768];
    const int tid = threadIdx.x;
    const int wid = tid >> 6;        // 0..3
    const int lane = tid & 63;
    const int col16 = lane & 15;
    const int koct = lane >> 4;
    const int s3 = col16 & 7;
    const int rowblk = blockIdx.x & 255;
    const int half = blockIdx.x >> 8;
    const int rowbase = rowblk * 128 + wid * 32;

    f16x8 zf[2][8];
    #pragma unroll
    for (int g = 0; g < 2; ++g) {
        const float* zp = z + (size_t)(rowbase + g * 16 + col16) * DIM + koct * 8;
        #pragma unroll
        for (int dc = 0; dc < 8; ++dc) {
            float4 f0 = *(const float4*)(zp + dc * 32);
            float4 f1 = *(const float4*)(zp + dc * 32 + 4);
            f16x8 h;
            h[0] = (_Float16)f0.x; h[1] = (_Float16)f0.y;
            h[2] = (_Float16)f0.z; h[3] = (_Float16)f0.w;
            h[4] = (_Float16)f1.x; h[5] = (_Float16)f1.y;
            h[6] = (_Float16)f1.z; h[7] = (_Float16)f1.w;
            zf[g][dc] = h;
        }
    }

    unsigned k1[2][4], k2[2][4], k3[2][4];
    #pragma unroll
    for (int g = 0; g < 2; ++g)
        #pragma unroll
        for (int r = 0; r < 4; ++r) { k1[g][r] = k2[g][r] = k3[g][r] = 0xFFFFFFFFu; }

    auto STAGE = [&](int tt, int b) {
        #pragma unroll
        for (int r = 0; r < 8; ++r) {
            int p = r * 256 + tid;
            int src = p ^ ((p >> 5) & 7);          // inverse swizzle (involution)
            const char* sp = (const char*)e16 + (size_t)half * 262144
                             + (size_t)tt * 32768 + src * 16;
            gload_lds16(sp, &lds[b][p * 16]);
        }
    };

    STAGE(0, 0);
    STAGE(1, 1);

    for (int tt = 0; tt < HALF_TILES; ++tt) {
        if (tt < HALF_TILES - 1)
            asm volatile("s_waitcnt vmcnt(8)" ::: "memory");
        else
            asm volatile("s_waitcnt vmcnt(0)" ::: "memory");
        __builtin_amdgcn_s_barrier();
        __builtin_amdgcn_sched_barrier(0);

        const char* bb = lds[tt & 1];
        f32x4 acc[2][4];
        #pragma unroll
        for (int ct = 0; ct < 4; ++ct) {
            float sv = sen[half * 512 + tt * TC + ct * 16 + col16];
            float b0 = fmaf(512.0f, sv, 512.0f);   // positive-bias C init
            acc[0][ct] = (f32x4){b0, b0, b0, b0};
            acc[1][ct] = (f32x4){b0, b0, b0, b0};
        }
        #pragma unroll
        for (int dc = 0; dc < 8; ++dc) {
            int swcol = ((dc * 4 + koct) ^ s3) * 16;
            #pragma unroll
            for (int ct = 0; ct < 4; ++ct) {
                int off = (ct * 16 + col16) * 512 + swcol;
                f16x8 bv = *(const f16x8*)(bb + off);
                acc[0][ct] = __builtin_amdgcn_mfma_f32_16x16x32_f16(zf[0][dc], bv, acc[0][ct], 0, 0, 0);
                acc[1][ct] = __builtin_amdgcn_mfma_f32_16x16x32_f16(zf[1][dc], bv, acc[1][ct], 0, 0, 0);
            }
        }
        #pragma unroll
        for (int ct = 0; ct < 4; ++ct) {
            const unsigned lidx = (unsigned)(tt * 4 + ct);
            #pragma unroll
            for (int g = 0; g < 2; ++g)
                #pragma unroll
                for (int r = 0; r < 4; ++r) {
                    float s = acc[g][ct][r];
                    unsigned key = (__float_as_uint(s) & 0xFFFFFFC0u) | lidx;
                    unsigned o1 = k1[g][r];
                    k1[g][r] = min(o1, key);                      // new min
                    k3[g][r] = min(k3[g][r], max(k2[g][r], key)); // new 3rd
                    k2[g][r] = min(max(key, o1), k2[g][r]);       // med
                }
        }

        __builtin_amdgcn_sched_barrier(0);
        __builtin_amdgcn_s_barrier();
        __builtin_amdgcn_sched_barrier(0);
        if (tt + 2 < HALF_TILES) STAGE(tt + 2, tt & 1);
    }

    #pragma unroll
    for (int g = 0; g < 2; ++g)
        #pragma unroll
        for (int r = 0; r < 4; ++r) {
            float a1 = __uint_as_float(k1[g][r] & 0xFFFFFFC0u);
            float a2 = __uint_as_float(k2[g][r] & 0xFFFFFFC0u);
            float a3 = __uint_as_float(k3[g][r] & 0xFFFFFFC0u);
            int l1 = (int)(k1[g][r] & 63u), l2 = (int)(k2[g][r] & 63u), l3 = (int)(k3[g][r] & 63u);
            int b1 = half * 512 + (l1 >> 2) * TC + (l1 & 3) * 16 + col16;
            int b2 = half * 512 + (l2 >> 2) * TC + (l2 & 3) * 16 + col16;
            int b3 = half * 512 + (l3 >> 2) * TC + (l3 & 3) * 16 + col16;
            #pragma unroll
            for (int m = 1; m < 16; m <<= 1) {
                float o1 = __shfl_xor(a1, m, 64), o2 = __shfl_xor(a2, m, 64), o3 = __shfl_xor(a3, m, 64);
                int p1 = __shfl_xor(b1, m, 64), p2 = __shfl_xor(b2, m, 64), p3 = __shfl_xor(b3, m, 64);
                #pragma unroll
                for (int k = 0; k < 3; ++k) {
                    float ov = (k == 0) ? o1 : (k == 1) ? o2 : o3;
                    int oi = (k == 0) ? p1 : (k == 1) ? p2 : p3;
                    if (lexless(ov, oi, a1, b1)) {
                        a3 = a2; b3 = b2; a2 = a1; b2 = b1; a1 = ov; b1 = oi;
                    } else if (lexless(ov, oi, a2, b2)) {
                        a3 = a2; b3 = b2; a2 = ov; b2 = oi;
                    } else if (lexless(ov, oi, a3, b3)) {
                        a3 = ov; b3 = oi;
                    }
                }
            }
            if (col16 == 0) {
                int row = rowbase + g * 16 + koct * 4 + r;
                unsigned* cp = cand + ((size_t)half * N_ROWS + row) * 6;
                cp[0] = __float_as_uint(a1); cp[1] = (unsigned)b1;
                cp[2] = __float_as_uint(a2); cp[3] = (unsigned)b2;
                cp[4] = __float_as_uint(a3); cp[5] = (unsigned)b3;
            }
        }
}

// merge the two halves' top-3 -> global top-3; classify pair/full.
__global__ __launch_bounds__(256) void vq_merge(const unsigned* __restrict__ cand,
                                                float* __restrict__ idx_out,
                                                unsigned* __restrict__ pcnt,
                                                uint2* __restrict__ pairlist,
                                                unsigned* __restrict__ fcnt,
                                                unsigned* __restrict__ fulllist,
                                                u64* __restrict__ fullkey) {
    int row = blockIdx.x * 256 + threadIdx.x;
    const unsigned* cA = cand + (size_t)row * 6;
    const unsigned* cB = cand + ((size_t)N_ROWS + row) * 6;
    float a1 = __uint_as_float(cA[0]), a2 = __uint_as_float(cA[2]), a3 = __uint_as_float(cA[4]);
    int   b1 = (int)cA[1], b2 = (int)cA[3], b3 = (int)cA[5];
    float o1 = __uint_as_float(cB[0]), o2 = __uint_as_float(cB[2]), o3 = __uint_as_float(cB[4]);
    int   p1 = (int)cB[1], p2 = (int)cB[3], p3 = (int)cB[5];
    #pragma unroll
    for (int k = 0; k < 3; ++k) {
        float ov = (k == 0) ? o1 : (k == 1) ? o2 : o3;
        int oi = (k == 0) ? p1 : (k == 1) ? p2 : p3;
        if (lexless(ov, oi, a1, b1)) {
            a3 = a2; b3 = b2; a2 = a1; b2 = b1; a1 = ov; b1 = oi;
        } else if (lexless(ov, oi, a2, b2)) {
            a3 = a2; b3 = b2; a2 = ov; b2 = oi;
        } else if (lexless(ov, oi, a3, b3)) {
            a3 = ov; b3 = oi;
        }
    }
    idx_out[row] = (float)b1;
    if (a2 - a1 < AMBIG_S) {
        if (a3 - a1 < AMBIG_S) {               // >=2 contenders near a1
            unsigned slot = atomicAdd(fcnt, 1u);
            fulllist[slot] = (unsigned)row;
            fullkey[slot] = ~0ull;
        } else {                               // exactly one contender
            unsigned slot = atomicAdd(pcnt, 1u);
            pairlist[slot] = make_uint2((unsigned)row,
                                        ((unsigned)b1 << 16) | (unsigned)b2);
        }
    }
}

// np-pairwise ||z||^2, replicated in every 16-lane group (global ptr OK).
__device__ inline float szn_wave(const float* __restrict__ zrow, int lane) {
    int sub = lane & 15;
    int hb = sub >> 3;
    int j = sub & 7;
    const float* a = zrow + hb * 128 + j;
    float v0 = a[0];
    float c = __fmul_rn(v0, v0);
    #pragma unroll
    for (int i = 1; i < 16; ++i) {
        float w = a[8 * i];
        c = __fadd_rn(c, __fmul_rn(w, w));
    }
    float p;
    p = __shfl_xor(c, 1, 64); c = __fadd_rn(c, p);
    p = __shfl_xor(c, 2, 64); c = __fadd_rn(c, p);
    p = __shfl_xor(c, 4, 64); c = __fadd_rn(c, p);
    p = __shfl_xor(c, 8, 64); c = __fadd_rn(c, p);
    return c;
}

// fused fix: blocks [0,768) pair rescore (wave/row); blocks [768,1024) full
// rescan (wave = (slot, 64-code chunk), lane = code, no LDS). The chunk that
// completes a slot's 16 atomicMins (fulldone==15) reads the final key with a
// no-op atomicMin and writes idx directly (vq_resolve eliminated).
__global__ __launch_bounds__(256) void vq_fix(const float* __restrict__ z,
                                              const float* __restrict__ cb,
                                              const float* __restrict__ sen,
                                              const unsigned* __restrict__ pcnt,
                                              const uint2* __restrict__ pairlist,
                                              const unsigned* __restrict__ fcnt,
                                              const unsigned* __restrict__ fulllist,
                                              u64* __restrict__ fullkey,
                                              unsigned* __restrict__ fulldone,
                                              float* __restrict__ idx_out) {
    const int lane = threadIdx.x & 63;
    const int wid = threadIdx.x >> 6;
    if (blockIdx.x < PAIR_GRID) {
        int wave = blockIdx.x * 4 + wid;
        int half = lane >> 5, s5 = lane & 31;
        int n = (int)*pcnt;
        for (int w = wave; w < n; w += PAIR_GRID * 4) {
            uint2 pr = pairlist[w];
            int row = (int)pr.x;
            int c1 = (int)(pr.y >> 16), c2 = (int)(pr.y & 0xffffu);
            const float* zrow = z + (size_t)row * DIM;
            float sz = szn_wave(zrow, lane);
            int c = half ? c2 : c1;
            const float* zp = zrow + s5 * 8;
            const float* ep = cb + (size_t)c * DIM + s5 * 8;
            float4 za = *(const float4*)zp, zb = *(const float4*)(zp + 4);
            float4 ea = *(const float4*)ep, eb = *(const float4*)(ep + 4);
            double acc = (double)ea.x * za.x + (double)ea.y * za.y
                       + (double)ea.z * za.z + (double)ea.w * za.w
                       + (double)eb.x * zb.x + (double)eb.y * zb.y
                       + (double)eb.z * zb.z + (double)eb.w * zb.w;
            #pragma unroll
            for (int m = 1; m < 32; m <<= 1) acc += __shfl_xor(acc, m, 64);
            double d2 = __shfl(acc, 32, 64);            // lane0 reads half-1 dot
            if (lane == 0) {
                float A1 = __fadd_rn(sz, sen[c1]);
                float dref1 = __fmaf_rn(-2.0f, (float)acc, A1);
                float A2 = __fadd_rn(sz, sen[c2]);
                float dref2 = __fmaf_rn(-2.0f, (float)d2, A2);
                int win = lexless(dref1, c1, dref2, c2) ? c1 : c2;
                idx_out[row] = (float)win;
            }
        }
    } else {
        unsigned nitems = (*fcnt) * 16u;
        for (unsigned item = (blockIdx.x - PAIR_GRID) * 4 + wid; item < nitems;
             item += (FIX_GRID - PAIR_GRID) * 4) {
            int slot = (int)(item >> 4);
            int row = (int)fulllist[slot];
            int c0 = (int)(item & 15u) * 64;
            const float* zrow = z + (size_t)row * DIM;
            float sz = szn_wave(zrow, lane);
            int c = c0 + lane;                          // lane = code
            const float* e = cb + (size_t)c * DIM;
            double a0 = 0.0, a1 = 0.0, a2 = 0.0, a3 = 0.0;
            #pragma unroll 8
            for (int d = 0; d < DIM; d += 4) {
                float4 zv = *(const float4*)(zrow + d);  // broadcast
                float4 ev = *(const float4*)(e + d);
                a0 += (double)ev.x * zv.x;
                a1 += (double)ev.y * zv.y;
                a2 += (double)ev.z * zv.z;
                a3 += (double)ev.w * zv.w;
            }
            double dot = (a0 + a1) + (a2 + a3);
            float A = __fadd_rn(sz, sen[c]);
            float dref = __fmaf_rn(-2.0f, (float)dot, A);
            float bv = dref; int bi = c;
            #pragma unroll
            for (int m = 1; m < 64; m <<= 1) {
                float ov = __shfl_xor(bv, m, 64);
                int oi = __shfl_xor(bi, m, 64);
                if (lexless(ov, oi, bv, bi)) { bv = ov; bi = oi; }
            }
            if (lane == 0) {
                u64 key = ((u64)__float_as_uint(bv) << 32) | (unsigned)bi;
                atomicMin(&fullkey[slot], key);
                unsigned d = atomicAdd(&fulldone[slot], 1u);
                if (d == 15u) {   // all 16 mins globally ordered before this
                    u64 fin = atomicMin(&fullkey[slot], ~0ull);  // no-op read
                    idx_out[row] = (float)(unsigned)(fin & 0xFFFFFFFFu);
                }
            }
        }
    }
}

// quantized_ste + commitment loss + histogram; LAST block (gdone) folds in
// the final loss/entropy reduction (finalize kernel eliminated). Cross-block
// data exchanged only via device-scope atomics (G16-safe).
__global__ __launch_bounds__(256) void vq_gather(const float* __restrict__ z,
                                                 const float* __restrict__ cb,
                                                 const float* __restrict__ idxf,
                                                 float* __restrict__ qout,
                                                 unsigned* __restrict__ hist,
                                                 double* __restrict__ partials,
                                                 unsigned* __restrict__ gdone,
                                                 float* __restrict__ out) {
    const int tid = threadIdx.x;
    double lacc = 0.0;
    #pragma unroll
    for (int it = 0; it < GATHER_ITERS; ++it) {
        int g = it * (GATHER_BLOCKS * 256) + blockIdx.x * 256 + tid;
        int row = g >> 6, c4 = g & 63;
        int idx = (int)idxf[row];
        if (c4 == 0) atomicAdd(&hist[idx], 1u);
        float4 zv = *(const float4*)(z + (size_t)g * 4);
        float4 qv = *(const float4*)(cb + (size_t)idx * DIM + c4 * 4);
        float dx = qv.x - zv.x, dy = qv.y - zv.y, dz = qv.z - zv.z, dw = qv.w - zv.w;
        float4 o;
        o.x = zv.x + dx; o.y = zv.y + dy; o.z = zv.z + dz; o.w = zv.w + dw;
        *(float4*)(qout + (size_t)g * 4) = o;
        lacc += (double)(dx * dx + dy * dy + dz * dz + dw * dw);
    }
    #pragma unroll
    for (int off = 32; off; off >>= 1) lacc += __shfl_down(lacc, off, 64);
    __shared__ double wsum[4];
    __shared__ int lastflag;
    int lane = tid & 63, wv = tid >> 6;
    if (lane == 0) wsum[wv] = lacc;
    __syncthreads();
    if (tid == 0) {
        double blk = (wsum[0] + wsum[1]) + (wsum[2] + wsum[3]);
        atomicExch((u64*)&partials[blockIdx.x],
                   (u64)__double_as_longlong(blk));   // device-scope store
        __threadfence();
        unsigned d = atomicAdd(gdone, 1u);
        lastflag = (d == GATHER_BLOCKS - 1u) ? 1 : 0;
    }
    __syncthreads();
    if (!lastflag) return;

    // final reduction (runs once, in the last-finishing block)
    __shared__ double rd[256];
    __shared__ float rf[256];
    double ds = 0.0;
    float fs = 0.0f;
    for (int i = tid; i < 1024; i += 256) {
        u64 raw = atomicOr((u64*)&partials[i], 0ull);          // atomic read
        ds += __longlong_as_double((long long)raw);
        unsigned h = atomicOr(&hist[i], 0u);                   // atomic read
        float p = (float)h * (1.0f / (float)N_ROWS);
        fs += p * logf(p + 1e-10f);
    }
    rd[tid] = ds; rf[tid] = fs;
    __syncthreads();
    for (int s = 128; s; s >>= 1) {
        if (tid < s) { rd[tid] += rd[tid + s]; rf[tid] += rf[tid + s]; }
        __syncthreads();
    }
    if (tid == 0) {
        out[ZERO_OFF] = 0.0f;
        out[LOSS_OFF] = (float)(0.25 * rd[0] / (double)Q_N);
        out[PERP_OFF] = expf(-rf[0]);
    }
}

extern "C" void kernel_launch(void* const* d_in, const int* in_sizes, int n_in,
                              void* d_out, int out_size, void* d_ws, size_t ws_size,
                              hipStream_t stream) {
    const float* z = (const float*)d_in[0];
    const float* cb = (const float*)d_in[1];
    float* out = (float*)d_out;

    float* sen = (float*)d_ws;
    unsigned* hist = (unsigned*)((char*)d_ws + 4096);
    unsigned* pcnt = (unsigned*)((char*)d_ws + 8192);
    unsigned* fcnt = (unsigned*)((char*)d_ws + 8196);
    unsigned* gdone = (unsigned*)((char*)d_ws + 8200);
    uint2* pairlist = (uint2*)((char*)d_ws + 8448);
    unsigned* fulllist = (unsigned*)((char*)d_ws + 270592);
    u16* e16 = (u16*)((char*)d_ws + 401664);
    double* partials = (double*)((char*)d_ws + 925952);
    u64* fullkey = (u64*)((char*)d_ws + 934144);
    unsigned* fulldone = (unsigned*)((char*)d_ws + 1196288);
    unsigned* cand = (unsigned*)d_out;   // q region = scratch until vq_gather

    vq_prep_cb<<<KCODES / 4, 256, 0, stream>>>(cb, sen, e16, hist, pcnt, fcnt, gdone, fulldone);
    vq_mfma<<<512, 256, 0, stream>>>(z, e16, sen, cand);
    vq_merge<<<N_ROWS / 256, 256, 0, stream>>>(cand, out + IDX_OFF,
                                               pcnt, pairlist, fcnt, fulllist, fullkey);
    vq_fix<<<FIX_GRID, 256, 0, stream>>>(z, cb, sen, pcnt, pairlist,
                                         fcnt, fulllist, fullkey, fulldone, out + IDX_OFF);
    vq_gather<<<GATHER_BLOCKS, 256, 0, stream>>>(z, cb, out + IDX_OFF, out, hist,
                                                 partials, gdone, out);
}

// Round 21
// 96.151 us; speedup vs baseline: 1.6985x; 1.3130x over previous
//
#include <hip/hip_runtime.h>

#define N_ROWS 32768
#define DIM 256
#define KCODES 1024

#define Q_N (N_ROWS * DIM)          // 8388608
#define IDX_OFF Q_N                 // 8388608
#define ZERO_OFF (Q_N + N_ROWS)     // 8421376
#define LOSS_OFF (ZERO_OFF + 1)
#define PERP_OFF (ZERO_OFF + 2)

// Scaled-acc units: acc' = 512 + 512*sen - 1024*dot (=1024*(score/2)+512).
// Required window T = np-flip window (0.031) + 2*fast-path error (~0.027)
// + 2*key-trunc (2*0.0039) ~= 0.093. AMBIG_S = 0.12 covers with slack.
#define AMBIG_S  0.12f

#define TC 64                 // codes per LDS tile (mfma)
#define HALF_TILES 8          // tiles per codebook half (512 codes)
#define PAIR_GRID 768
#define FIX_GRID 1024         // [0,768) pair, [768,1024) full
#define GATHER_BLOCKS 1024
#define GATHER_ITERS 8        // 1024*256*8 = 2M float4 = N_ROWS*DIM/4

typedef __attribute__((ext_vector_type(8))) _Float16 f16x8;
typedef __attribute__((ext_vector_type(4))) float f32x4;
typedef unsigned short u16;
typedef unsigned long long u64;

// ws layout (bytes)  [identical to round 18's proven 2.77MB footprint]:
//   [0, 4096)            sen float[K]
//   [4096, 8192)         hist uint[K]
//   [8192, 8196)         uint pair_count
//   [8196, 8200)         uint full_count
//   [8448, 270592)       pairlist uint2[32768]  {row, c1<<16|c2}
//   [270592, 401664)     fulllist uint[32768]
//   [401664, 925952)     e16 u16[262144]  (fp16 of -1024*e, row-major)
//   [925952, 934144)     partials double[1024]  (per-block loss sums)
//   [934144, 1196288)    fullkey u64[32768]  (per-fulllist-slot packed min)
//   [1196288, 2769152)   cand u32[2][32768][6]  (per-half top-3)  -- in WS,
//                        NOT d_out: q-region aliasing caused round-20's
//                        gather regression (remote-dirty L2 lines on store)

__device__ inline u16 f16bits(_Float16 h) {
    union { _Float16 h; u16 u; } x; x.h = h; return x.u;
}

__device__ inline bool lexless(float av, int ai, float bv, int bi) {
    return av < bv || (av == bv && ai < bi);
}

typedef __attribute__((address_space(3))) unsigned int as3_uint;
typedef __attribute__((address_space(1))) const unsigned int as1_uint;
__device__ inline void gload_lds16(const void* g, void* l) {
    __builtin_amdgcn_global_load_lds((as1_uint*)g, (as3_uint*)l, 16, 0, 0);
}

// fused: init(hist/counters) + accurate ||e||^2 + e16 = fp16(-1024*e).
__global__ __launch_bounds__(256) void vq_prep_cb(const float* __restrict__ cb,
                                                  float* __restrict__ sen,
                                                  u16* __restrict__ e16,
                                                  unsigned* __restrict__ hist,
                                                  unsigned* __restrict__ pcnt,
                                                  unsigned* __restrict__ fcnt) {
    int b = blockIdx.x, t = threadIdx.x;
    if (b < 4) {
        hist[b * 256 + t] = 0u;
        if (b == 0 && t == 0) { *pcnt = 0u; *fcnt = 0u; }
    }
    int code = b * 4 + (t >> 6);
    int lane = t & 63;
    size_t eoff = (size_t)code * DIM + lane * 4;
    float4 v = *(const float4*)(cb + eoff);
    double s = (double)v.x * v.x + (double)v.y * v.y + (double)v.z * v.z + (double)v.w * v.w;
    #pragma unroll
    for (int off = 32; off; off >>= 1) s += __shfl_down(s, off, 64);
    if (lane == 0) sen[code] = (float)s;
    ushort4 us;
    us.x = f16bits((_Float16)(-1024.0f * v.x));
    us.y = f16bits((_Float16)(-1024.0f * v.y));
    us.z = f16bits((_Float16)(-1024.0f * v.z));
    us.w = f16bits((_Float16)(-1024.0f * v.w));
    *(ushort4*)(e16 + eoff) = us;
}

// fp16 MFMA distance-argmin, SPLIT-K halves + counted-vmcnt barriers
// (round-18 version verbatim: best measured structure, ~48us).
__global__ __launch_bounds__(256, 2) void vq_mfma(const float* __restrict__ z,
                                                  const u16* __restrict__ e16,
                                                  const float* __restrict__ sen,
                                                  unsigned* __restrict__ cand) {
    __shared__ char lds[2][32768];
    const int tid = threadIdx.x;
    const int wid = tid >> 6;        // 0..3
    const int lane = tid & 63;
    const int col16 = lane & 15;
    const int koct = lane >> 4;
    const int s3 = col16 & 7;
    const int rowblk = blockIdx.x & 255;
    const int half = blockIdx.x >> 8;
    const int rowbase = rowblk * 128 + wid * 32;

    f16x8 zf[2][8];
    #pragma unroll
    for (int g = 0; g < 2; ++g) {
        const float* zp = z + (size_t)(rowbase + g * 16 + col16) * DIM + koct * 8;
        #pragma unroll
        for (int dc = 0; dc < 8; ++dc) {
            float4 f0 = *(const float4*)(zp + dc * 32);
            float4 f1 = *(const float4*)(zp + dc * 32 + 4);
            f16x8 h;
            h[0] = (_Float16)f0.x; h[1] = (_Float16)f0.y;
            h[2] = (_Float16)f0.z; h[3] = (_Float16)f0.w;
            h[4] = (_Float16)f1.x; h[5] = (_Float16)f1.y;
            h[6] = (_Float16)f1.z; h[7] = (_Float16)f1.w;
            zf[g][dc] = h;
        }
    }

    unsigned k1[2][4], k2[2][4], k3[2][4];
    #pragma unroll
    for (int g = 0; g < 2; ++g)
        #pragma unroll
        for (int r = 0; r < 4; ++r) { k1[g][r] = k2[g][r] = k3[g][r] = 0xFFFFFFFFu; }

    auto STAGE = [&](int tt, int b) {
        #pragma unroll
        for (int r = 0; r < 8; ++r) {
            int p = r * 256 + tid;
            int src = p ^ ((p >> 5) & 7);          // inverse swizzle (involution)
            const char* sp = (const char*)e16 + (size_t)half * 262144
                             + (size_t)tt * 32768 + src * 16;
            gload_lds16(sp, &lds[b][p * 16]);
        }
    };

    STAGE(0, 0);
    STAGE(1, 1);

    for (int tt = 0; tt < HALF_TILES; ++tt) {
        if (tt < HALF_TILES - 1)
            asm volatile("s_waitcnt vmcnt(8)" ::: "memory");
        else
            asm volatile("s_waitcnt vmcnt(0)" ::: "memory");
        __builtin_amdgcn_s_barrier();
        __builtin_amdgcn_sched_barrier(0);

        const char* bb = lds[tt & 1];
        f32x4 acc[2][4];
        #pragma unroll
        for (int ct = 0; ct < 4; ++ct) {
            float sv = sen[half * 512 + tt * TC + ct * 16 + col16];
            float b0 = fmaf(512.0f, sv, 512.0f);   // positive-bias C init
            acc[0][ct] = (f32x4){b0, b0, b0, b0};
            acc[1][ct] = (f32x4){b0, b0, b0, b0};
        }
        #pragma unroll
        for (int dc = 0; dc < 8; ++dc) {
            int swcol = ((dc * 4 + koct) ^ s3) * 16;
            #pragma unroll
            for (int ct = 0; ct < 4; ++ct) {
                int off = (ct * 16 + col16) * 512 + swcol;
                f16x8 bv = *(const f16x8*)(bb + off);
                acc[0][ct] = __builtin_amdgcn_mfma_f32_16x16x32_f16(zf[0][dc], bv, acc[0][ct], 0, 0, 0);
                acc[1][ct] = __builtin_amdgcn_mfma_f32_16x16x32_f16(zf[1][dc], bv, acc[1][ct], 0, 0, 0);
            }
        }
        #pragma unroll
        for (int ct = 0; ct < 4; ++ct) {
            const unsigned lidx = (unsigned)(tt * 4 + ct);
            #pragma unroll
            for (int g = 0; g < 2; ++g)
                #pragma unroll
                for (int r = 0; r < 4; ++r) {
                    float s = acc[g][ct][r];
                    unsigned key = (__float_as_uint(s) & 0xFFFFFFC0u) | lidx;
                    unsigned o1 = k1[g][r];
                    k1[g][r] = min(o1, key);                      // new min
                    k3[g][r] = min(k3[g][r], max(k2[g][r], key)); // new 3rd
                    k2[g][r] = min(max(key, o1), k2[g][r]);       // med
                }
        }

        __builtin_amdgcn_sched_barrier(0);
        __builtin_amdgcn_s_barrier();
        __builtin_amdgcn_sched_barrier(0);
        if (tt + 2 < HALF_TILES) STAGE(tt + 2, tt & 1);
    }

    #pragma unroll
    for (int g = 0; g < 2; ++g)
        #pragma unroll
        for (int r = 0; r < 4; ++r) {
            float a1 = __uint_as_float(k1[g][r] & 0xFFFFFFC0u);
            float a2 = __uint_as_float(k2[g][r] & 0xFFFFFFC0u);
            float a3 = __uint_as_float(k3[g][r] & 0xFFFFFFC0u);
            int l1 = (int)(k1[g][r] & 63u), l2 = (int)(k2[g][r] & 63u), l3 = (int)(k3[g][r] & 63u);
            int b1 = half * 512 + (l1 >> 2) * TC + (l1 & 3) * 16 + col16;
            int b2 = half * 512 + (l2 >> 2) * TC + (l2 & 3) * 16 + col16;
            int b3 = half * 512 + (l3 >> 2) * TC + (l3 & 3) * 16 + col16;
            #pragma unroll
            for (int m = 1; m < 16; m <<= 1) {
                float o1 = __shfl_xor(a1, m, 64), o2 = __shfl_xor(a2, m, 64), o3 = __shfl_xor(a3, m, 64);
                int p1 = __shfl_xor(b1, m, 64), p2 = __shfl_xor(b2, m, 64), p3 = __shfl_xor(b3, m, 64);
                #pragma unroll
                for (int k = 0; k < 3; ++k) {
                    float ov = (k == 0) ? o1 : (k == 1) ? o2 : o3;
                    int oi = (k == 0) ? p1 : (k == 1) ? p2 : p3;
                    if (lexless(ov, oi, a1, b1)) {
                        a3 = a2; b3 = b2; a2 = a1; b2 = b1; a1 = ov; b1 = oi;
                    } else if (lexless(ov, oi, a2, b2)) {
                        a3 = a2; b3 = b2; a2 = ov; b2 = oi;
                    } else if (lexless(ov, oi, a3, b3)) {
                        a3 = ov; b3 = oi;
                    }
                }
            }
            if (col16 == 0) {
                int row = rowbase + g * 16 + koct * 4 + r;
                unsigned* cp = cand + ((size_t)half * N_ROWS + row) * 6;
                cp[0] = __float_as_uint(a1); cp[1] = (unsigned)b1;
                cp[2] = __float_as_uint(a2); cp[3] = (unsigned)b2;
                cp[4] = __float_as_uint(a3); cp[5] = (unsigned)b3;
            }
        }
}

// merge the two halves' top-3 -> global top-3; classify pair/full.
__global__ __launch_bounds__(256) void vq_merge(const unsigned* __restrict__ cand,
                                                float* __restrict__ idx_out,
                                                unsigned* __restrict__ pcnt,
                                                uint2* __restrict__ pairlist,
                                                unsigned* __restrict__ fcnt,
                                                unsigned* __restrict__ fulllist,
                                                u64* __restrict__ fullkey) {
    int row = blockIdx.x * 256 + threadIdx.x;
    const unsigned* cA = cand + (size_t)row * 6;
    const unsigned* cB = cand + ((size_t)N_ROWS + row) * 6;
    float a1 = __uint_as_float(cA[0]), a2 = __uint_as_float(cA[2]), a3 = __uint_as_float(cA[4]);
    int   b1 = (int)cA[1], b2 = (int)cA[3], b3 = (int)cA[5];
    float o1 = __uint_as_float(cB[0]), o2 = __uint_as_float(cB[2]), o3 = __uint_as_float(cB[4]);
    int   p1 = (int)cB[1], p2 = (int)cB[3], p3 = (int)cB[5];
    #pragma unroll
    for (int k = 0; k < 3; ++k) {
        float ov = (k == 0) ? o1 : (k == 1) ? o2 : o3;
        int oi = (k == 0) ? p1 : (k == 1) ? p2 : p3;
        if (lexless(ov, oi, a1, b1)) {
            a3 = a2; b3 = b2; a2 = a1; b2 = b1; a1 = ov; b1 = oi;
        } else if (lexless(ov, oi, a2, b2)) {
            a3 = a2; b3 = b2; a2 = ov; b2 = oi;
        } else if (lexless(ov, oi, a3, b3)) {
            a3 = ov; b3 = oi;
        }
    }
    idx_out[row] = (float)b1;
    if (a2 - a1 < AMBIG_S) {
        if (a3 - a1 < AMBIG_S) {               // >=2 contenders near a1
            unsigned slot = atomicAdd(fcnt, 1u);
            fulllist[slot] = (unsigned)row;
            fullkey[slot] = ~0ull;
        } else {                               // exactly one contender
            unsigned slot = atomicAdd(pcnt, 1u);
            pairlist[slot] = make_uint2((unsigned)row,
                                        ((unsigned)b1 << 16) | (unsigned)b2);
        }
    }
}

// np-pairwise ||z||^2, replicated in every 16-lane group.
__device__ inline float szn_wave(const float* __restrict__ zrow, int lane) {
    int sub = lane & 15;
    int hb = sub >> 3;
    int j = sub & 7;
    const float* a = zrow + hb * 128 + j;
    float v0 = a[0];
    float c = __fmul_rn(v0, v0);
    #pragma unroll
    for (int i = 1; i < 16; ++i) {
        float w = a[8 * i];
        c = __fadd_rn(c, __fmul_rn(w, w));
    }
    float p;
    p = __shfl_xor(c, 1, 64); c = __fadd_rn(c, p);
    p = __shfl_xor(c, 2, 64); c = __fadd_rn(c, p);
    p = __shfl_xor(c, 4, 64); c = __fadd_rn(c, p);
    p = __shfl_xor(c, 8, 64); c = __fadd_rn(c, p);
    return c;
}

// fused fix: blocks [0,768) pair rescore (wave/row, concurrent with) blocks
// [768,1024) full rescan (wave = (slot, 64-code chunk), lane = code, no LDS;
// atomicMin only — idx written by vq_resolve).
__global__ __launch_bounds__(256) void vq_fix(const float* __restrict__ z,
                                              const float* __restrict__ cb,
                                              const float* __restrict__ sen,
                                              const unsigned* __restrict__ pcnt,
                                              const uint2* __restrict__ pairlist,
                                              const unsigned* __restrict__ fcnt,
                                              const unsigned* __restrict__ fulllist,
                                              u64* __restrict__ fullkey,
                                              float* __restrict__ idx_out) {
    const int lane = threadIdx.x & 63;
    const int wid = threadIdx.x >> 6;
    if (blockIdx.x < PAIR_GRID) {
        int wave = blockIdx.x * 4 + wid;
        int half = lane >> 5, s5 = lane & 31;
        int n = (int)*pcnt;
        for (int w = wave; w < n; w += PAIR_GRID * 4) {
            uint2 pr = pairlist[w];
            int row = (int)pr.x;
            int c1 = (int)(pr.y >> 16), c2 = (int)(pr.y & 0xffffu);
            const float* zrow = z + (size_t)row * DIM;
            float sz = szn_wave(zrow, lane);
            int c = half ? c2 : c1;
            const float* zp = zrow + s5 * 8;
            const float* ep = cb + (size_t)c * DIM + s5 * 8;
            float4 za = *(const float4*)zp, zb = *(const float4*)(zp + 4);
            float4 ea = *(const float4*)ep, eb = *(const float4*)(ep + 4);
            double acc = (double)ea.x * za.x + (double)ea.y * za.y
                       + (double)ea.z * za.z + (double)ea.w * za.w
                       + (double)eb.x * zb.x + (double)eb.y * zb.y
                       + (double)eb.z * zb.z + (double)eb.w * zb.w;
            #pragma unroll
            for (int m = 1; m < 32; m <<= 1) acc += __shfl_xor(acc, m, 64);
            double d2 = __shfl(acc, 32, 64);            // lane0 reads half-1 dot
            if (lane == 0) {
                float A1 = __fadd_rn(sz, sen[c1]);
                float dref1 = __fmaf_rn(-2.0f, (float)acc, A1);
                float A2 = __fadd_rn(sz, sen[c2]);
                float dref2 = __fmaf_rn(-2.0f, (float)d2, A2);
                int win = lexless(dref1, c1, dref2, c2) ? c1 : c2;
                idx_out[row] = (float)win;
            }
        }
    } else {
        unsigned nitems = (*fcnt) * 16u;
        for (unsigned item = (blockIdx.x - PAIR_GRID) * 4 + wid; item < nitems;
             item += (FIX_GRID - PAIR_GRID) * 4) {
            int slot = (int)(item >> 4);
            int row = (int)fulllist[slot];
            int c0 = (int)(item & 15u) * 64;
            const float* zrow = z + (size_t)row * DIM;
            float sz = szn_wave(zrow, lane);
            int c = c0 + lane;                          // lane = code
            const float* e = cb + (size_t)c * DIM;
            double a0 = 0.0, a1 = 0.0, a2 = 0.0, a3 = 0.0;
            #pragma unroll 8
            for (int d = 0; d < DIM; d += 4) {
                float4 zv = *(const float4*)(zrow + d);  // broadcast
                float4 ev = *(const float4*)(e + d);
                a0 += (double)ev.x * zv.x;
                a1 += (double)ev.y * zv.y;
                a2 += (double)ev.z * zv.z;
                a3 += (double)ev.w * zv.w;
            }
            double dot = (a0 + a1) + (a2 + a3);
            float A = __fadd_rn(sz, sen[c]);
            float dref = __fmaf_rn(-2.0f, (float)dot, A);
            float bv = dref; int bi = c;
            #pragma unroll
            for (int m = 1; m < 64; m <<= 1) {
                float ov = __shfl_xor(bv, m, 64);
                int oi = __shfl_xor(bi, m, 64);
                if (lexless(ov, oi, bv, bi)) { bv = ov; bi = oi; }
            }
            if (lane == 0) {
                u64 key = ((u64)__float_as_uint(bv) << 32) | (unsigned)bi;
                atomicMin(&fullkey[slot], key);
            }
        }
    }
}

// unpack per-slot winners -> idx (runs after fix, before gather)
__global__ __launch_bounds__(256) void vq_resolve(const unsigned* __restrict__ fcnt,
                                                  const unsigned* __restrict__ fulllist,
                                                  const u64* __restrict__ fullkey,
                                                  float* __restrict__ idx_out) {
    int n = (int)*fcnt;
    for (int i = threadIdx.x; i < n; i += 256)
        idx_out[fulllist[i]] = (float)(unsigned)(fullkey[i] & 0xFFFFFFFFu);
}

// quantized_ste + commitment loss + histogram. Per-block loss partials
// (plain stores; round-18 version verbatim).
__global__ __launch_bounds__(256) void vq_gather(const float* __restrict__ z,
                                                 const float* __restrict__ cb,
                                                 const float* __restrict__ idxf,
                                                 float* __restrict__ qout,
                                                 unsigned* __restrict__ hist,
                                                 double* __restrict__ partials) {
    const int tid = threadIdx.x;
    double lacc = 0.0;
    #pragma unroll
    for (int it = 0; it < GATHER_ITERS; ++it) {
        int g = it * (GATHER_BLOCKS * 256) + blockIdx.x * 256 + tid;
        int row = g >> 6, c4 = g & 63;
        int idx = (int)idxf[row];
        if (c4 == 0) atomicAdd(&hist[idx], 1u);
        float4 zv = *(const float4*)(z + (size_t)g * 4);
        float4 qv = *(const float4*)(cb + (size_t)idx * DIM + c4 * 4);
        float dx = qv.x - zv.x, dy = qv.y - zv.y, dz = qv.z - zv.z, dw = qv.w - zv.w;
        float4 o;
        o.x = zv.x + dx; o.y = zv.y + dy; o.z = zv.z + dz; o.w = zv.w + dw;
        *(float4*)(qout + (size_t)g * 4) = o;
        lacc += (double)(dx * dx + dy * dy + dz * dz + dw * dw);
    }
    #pragma unroll
    for (int off = 32; off; off >>= 1) lacc += __shfl_down(lacc, off, 64);
    __shared__ double wsum[4];
    int lane = tid & 63, wv = tid >> 6;
    if (lane == 0) wsum[wv] = lacc;
    __syncthreads();
    if (tid == 0)
        partials[blockIdx.x] = (wsum[0] + wsum[1]) + (wsum[2] + wsum[3]);
}

// reduce 1024 loss partials (double) + hist entropy -> 3 scalars
__global__ __launch_bounds__(1024) void vq_finalize(const unsigned* __restrict__ hist,
                                                    const double* __restrict__ partials,
                                                    float* __restrict__ out) {
    __shared__ float red[1024];
    __shared__ double redd[1024];
    int t = threadIdx.x;
    float p = (float)hist[t] * (1.0f / (float)N_ROWS);
    red[t] = p * logf(p + 1e-10f);
    redd[t] = partials[t];
    __syncthreads();
    for (int s = 512; s; s >>= 1) {
        if (t < s) { red[t] += red[t + s]; redd[t] += redd[t + s]; }
        __syncthreads();
    }
    if (t == 0) {
        out[ZERO_OFF] = 0.0f;
        out[LOSS_OFF] = (float)(0.25 * redd[0] / (double)Q_N);
        out[PERP_OFF] = expf(-red[0]);
    }
}

extern "C" void kernel_launch(void* const* d_in, const int* in_sizes, int n_in,
                              void* d_out, int out_size, void* d_ws, size_t ws_size,
                              hipStream_t stream) {
    const float* z = (const float*)d_in[0];
    const float* cb = (const float*)d_in[1];
    float* out = (float*)d_out;

    float* sen = (float*)d_ws;
    unsigned* hist = (unsigned*)((char*)d_ws + 4096);
    unsigned* pcnt = (unsigned*)((char*)d_ws + 8192);
    unsigned* fcnt = (unsigned*)((char*)d_ws + 8196);
    uint2* pairlist = (uint2*)((char*)d_ws + 8448);
    unsigned* fulllist = (unsigned*)((char*)d_ws + 270592);
    u16* e16 = (u16*)((char*)d_ws + 401664);
    double* partials = (double*)((char*)d_ws + 925952);
    u64* fullkey = (u64*)((char*)d_ws + 934144);
    unsigned* cand = (unsigned*)((char*)d_ws + 1196288);

    vq_prep_cb<<<KCODES / 4, 256, 0, stream>>>(cb, sen, e16, hist, pcnt, fcnt);
    vq_mfma<<<512, 256, 0, stream>>>(z, e16, sen, cand);
    vq_merge<<<N_ROWS / 256, 256, 0, stream>>>(cand, out + IDX_OFF,
                                               pcnt, pairlist, fcnt, fulllist, fullkey);
    vq_fix<<<FIX_GRID, 256, 0, stream>>>(z, cb, sen, pcnt, pairlist,
                                         fcnt, fulllist, fullkey, out + IDX_OFF);
    vq_resolve<<<1, 256, 0, stream>>>(fcnt, fulllist, fullkey, out + IDX_OFF);
    vq_gather<<<GATHER_BLOCKS, 256, 0, stream>>>(z, cb, out + IDX_OFF, out, hist, partials);
    vq_finalize<<<1, 1024, 0, stream>>>(hist, partials, out);
}